// Round 1
// baseline (16947.328 us; speedup 1.0000x reference)
//
#include <hip/hip_runtime.h>

#define TLEN 512
#define HDIM 512
#define NGRP 8
#define MROW 32
#define NL0  8
#define WPG  24
#define GRID (NGRP*WPG)
#define U0   64
#define U1   32
#define HSZ  (MROW*HDIM)   // elements per h buffer (one parity) per group

typedef __attribute__((ext_vector_type(8))) short bf16x8;
typedef __attribute__((ext_vector_type(4))) float f32x4;

__device__ __forceinline__ unsigned short f2bf(float f){
  unsigned u = __builtin_bit_cast(unsigned, f);
  u = (u + 0x7FFFu + ((u>>16)&1u)) >> 16;   // RNE
  return (unsigned short)u;
}
__device__ __forceinline__ float sigm(float v){ return 1.f/(1.f + __expf(-v)); }
__device__ __forceinline__ float tanh_f(float v){ return 1.f - 2.f/(__expf(2.f*v)+1.f); }

extern "C" __global__ void __launch_bounds__(256,1)
gru_persistent(const float* __restrict__ x,
               const float* __restrict__ Wi0,
               const float* __restrict__ bi0,
               const float* __restrict__ Wi1,
               const float* __restrict__ bi1,
               const float* __restrict__ Wh,
               const float* __restrict__ bh,
               const float* __restrict__ fcw,
               const float* __restrict__ fcb,
               float* __restrict__ out,
               unsigned* __restrict__ bar,
               unsigned short* __restrict__ h0g,
               unsigned short* __restrict__ h1g,
               float* __restrict__ h1f)
{
  // LDS: staged A chunks (row stride 528B = 512B data + 16B pad) + gate sums
  __shared__ unsigned short shA[MROW*264];
  __shared__ unsigned short shB[MROW*264];
  __shared__ float shG[MROW*192];

  const int tid  = threadIdx.x;
  const int lane = tid & 63;
  const int w    = tid >> 6;
  const int grp  = blockIdx.x & 7;      // XCD-locality swizzle (perf heuristic only)
  const int wgid = blockIdx.x >> 3;     // 0..23
  const bool isL0 = (wgid < NL0);
  const int g32 = grp*32;

  unsigned* barp = bar + grp*64;                 // 256B-separated counters
  unsigned short* h0 = h0g + grp*2*HSZ;
  unsigned short* h1 = h1g + grp*2*HSZ;

  if (isL0){
    // ---------------- layer-0 workgroup: units [u0, u0+64) ----------------
    const int u0   = wgid*U0;
    const int colb = w*48;               // this wave's 48 cols of the 192 (col = g*64+u)

    // pin B fragments (weights, bf16) in VGPRs for the whole kernel
    bf16x8 bfr[3][16];
    #pragma unroll
    for (int nt=0; nt<3; ++nt){
      int col = colb + nt*16 + (lane&15);
      int g = col>>6, uu = col&63;
      const float* wrow = Wh + (size_t)(g*HDIM + u0 + uu)*HDIM;   // Wh[0][g][u][:]
      #pragma unroll
      for (int ks=0; ks<16; ++ks){
        int k = ks*32 + (lane>>4)*8;
        const float4 f0 = *(const float4*)(wrow + k);
        const float4 f1 = *(const float4*)(wrow + k + 4);
        bf16x8 v;
        v[0]=(short)f2bf(f0.x); v[1]=(short)f2bf(f0.y); v[2]=(short)f2bf(f0.z); v[3]=(short)f2bf(f0.w);
        v[4]=(short)f2bf(f1.x); v[5]=(short)f2bf(f1.y); v[6]=(short)f2bf(f1.z); v[7]=(short)f2bf(f1.w);
        bfr[nt][ks]=v;
      }
    }
    // activation-thread constants: this thread owns unit ua for 8 batch rows
    const int ua   = tid & 63;
    const int brow = (tid>>6)*8;
    float wi0v[3], bi0v[3], bh0v[3];
    #pragma unroll
    for (int g=0; g<3; ++g){
      wi0v[g] = Wi0[g*HDIM + u0+ua];
      bi0v[g] = bi0[g*HDIM + u0+ua];
      bh0v[g] = bh [g*HDIM + u0+ua];
    }
    float h_own[8];
    #pragma unroll
    for (int j=0;j<8;++j) h_own[j]=0.f;

    unsigned tgt = 0;
    for (int s=0; s<=TLEN; ++s){
      if (s < TLEN){
        const unsigned short* srcA = h0 + ((s-1)&1)*HSZ;   // h0(s-1)
        unsigned short*       dstA = h0 + (s&1)*HSZ;       // h0(s)
        const int rbase = w*8;
        uint4 st[4];
        #pragma unroll
        for (int i=0;i<4;++i){
          int r = rbase + 2*i + (lane>>5);
          st[i] = *(const uint4*)((const char*)srcA + r*1024 + (lane&31)*16);
        }
        #pragma unroll
        for (int i=0;i<4;++i){
          int r = rbase + 2*i + (lane>>5);
          *(uint4*)((char*)shA + r*528 + (lane&31)*16) = st[i];
        }
        __syncthreads();
        // prefetch chunk 1 while computing chunk 0
        #pragma unroll
        for (int i=0;i<4;++i){
          int r = rbase + 2*i + (lane>>5);
          st[i] = *(const uint4*)((const char*)srcA + r*1024 + 512 + (lane&31)*16);
        }
        f32x4 acc[2][3] = {};
        #pragma unroll
        for (int ks=0; ks<8; ++ks){
          int koff = (ks*32 + (lane>>4)*8)*2;
          bf16x8 a0 = *(const bf16x8*)((const char*)shA + (lane&15)*528 + koff);
          bf16x8 a1 = *(const bf16x8*)((const char*)shA + ((lane&15)+16)*528 + koff);
          #pragma unroll
          for (int nt=0; nt<3; ++nt){
            acc[0][nt] = __builtin_amdgcn_mfma_f32_16x16x32_bf16(a0, bfr[nt][ks], acc[0][nt],0,0,0);
            acc[1][nt] = __builtin_amdgcn_mfma_f32_16x16x32_bf16(a1, bfr[nt][ks], acc[1][nt],0,0,0);
          }
        }
        __syncthreads();
        #pragma unroll
        for (int i=0;i<4;++i){
          int r = rbase + 2*i + (lane>>5);
          *(uint4*)((char*)shA + r*528 + (lane&31)*16) = st[i];
        }
        __syncthreads();
        #pragma unroll
        for (int ks=0; ks<8; ++ks){
          int koff = (ks*32 + (lane>>4)*8)*2;
          bf16x8 a0 = *(const bf16x8*)((const char*)shA + (lane&15)*528 + koff);
          bf16x8 a1 = *(const bf16x8*)((const char*)shA + ((lane&15)+16)*528 + koff);
          #pragma unroll
          for (int nt=0; nt<3; ++nt){
            acc[0][nt] = __builtin_amdgcn_mfma_f32_16x16x32_bf16(a0, bfr[nt][8+ks], acc[0][nt],0,0,0);
            acc[1][nt] = __builtin_amdgcn_mfma_f32_16x16x32_bf16(a1, bfr[nt][8+ks], acc[1][nt],0,0,0);
          }
        }
        // dump gate sums: C layout row(b)=4*quad+reg, col=lane&15
        #pragma unroll
        for (int mt=0; mt<2; ++mt)
          #pragma unroll
          for (int nt=0; nt<3; ++nt)
            #pragma unroll
            for (int j=0;j<4;++j){
              int b = mt*16 + (lane>>4)*4 + j;
              shG[b*192 + colb + nt*16 + (lane&15)] = acc[mt][nt][j];
            }
        __syncthreads();
        // activation (fp32 own-state path)
        #pragma unroll
        for (int j=0;j<8;++j){
          int b = brow + j;
          float xv = x[(g32+b)*TLEN + s];
          float G0 = shG[b*192 + ua]       + bh0v[0];
          float G1 = shG[b*192 + 64 + ua]  + bh0v[1];
          float G2 = shG[b*192 + 128 + ua] + bh0v[2];
          float r_ = sigm(fmaf(xv, wi0v[0], bi0v[0]) + G0);
          float z_ = sigm(fmaf(xv, wi0v[1], bi0v[1]) + G1);
          float n_ = tanh_f(fmaf(xv, wi0v[2], bi0v[2]) + r_*G2);
          float hn = (1.f - z_)*n_ + z_*h_own[j];
          h_own[j] = hn;
          dstA[b*HDIM + u0 + ua] = f2bf(hn);
        }
      }
      tgt += WPG;
      __threadfence();
      __syncthreads();
      if (tid==0){
        __hip_atomic_fetch_add(barp, 1u, __ATOMIC_RELEASE, __HIP_MEMORY_SCOPE_AGENT);
        while (__hip_atomic_load(barp, __ATOMIC_RELAXED, __HIP_MEMORY_SCOPE_AGENT) < tgt)
          __builtin_amdgcn_s_sleep(1);
      }
      __syncthreads();
      __threadfence();
    }
    // final FC: 32 rows x 2 outputs, done by WG0 of the group
    if (wgid==0){
      int p = tid>>2, kl = tid&3;
      int b = p>>1, o = p&1;
      const float4* h4 = (const float4*)(h1f + (size_t)(g32+b)*HDIM + kl*128);
      const float4* w4 = (const float4*)(fcw + o*HDIM + kl*128);
      float a2 = 0.f;
      #pragma unroll
      for (int k=0;k<32;++k){
        float4 aa=h4[k], bb=w4[k];
        a2 = fmaf(aa.x,bb.x,a2); a2 = fmaf(aa.y,bb.y,a2);
        a2 = fmaf(aa.z,bb.z,a2); a2 = fmaf(aa.w,bb.w,a2);
      }
      a2 += __shfl_xor(a2, 1);
      a2 += __shfl_xor(a2, 2);
      if (kl==0) out[(g32+b)*2 + o] = a2 + fcb[o];
    }
  } else {
    // ---------------- layer-1 workgroup: units [u1, u1+32) ----------------
    const int u1   = (wgid-NL0)*U1;
    const int colb = (w<2) ? w*48 : 96 + (w-2)*48;  // cols 0..95 gi, 96..191 gh

    bf16x8 bfr[3][16];
    #pragma unroll
    for (int nt=0; nt<3; ++nt){
      int col = colb + nt*16 + (lane&15);
      const float* wrow;
      if (w < 2){ int g = col>>5, uu = col&31;
        wrow = Wi1 + (size_t)(g*HDIM + u1 + uu)*HDIM;             // Wi_rest[0][g][u][:]
      } else {    int c2 = col-96; int g = c2>>5, uu = c2&31;
        wrow = Wh + (size_t)((3+g)*HDIM + u1 + uu)*HDIM;          // Wh[1][g][u][:]
      }
      #pragma unroll
      for (int ks=0; ks<16; ++ks){
        int k = ks*32 + (lane>>4)*8;
        const float4 f0 = *(const float4*)(wrow + k);
        const float4 f1 = *(const float4*)(wrow + k + 4);
        bf16x8 v;
        v[0]=(short)f2bf(f0.x); v[1]=(short)f2bf(f0.y); v[2]=(short)f2bf(f0.z); v[3]=(short)f2bf(f0.w);
        v[4]=(short)f2bf(f1.x); v[5]=(short)f2bf(f1.y); v[6]=(short)f2bf(f1.z); v[7]=(short)f2bf(f1.w);
        bfr[nt][ks]=v;
      }
    }
    const int ua   = tid & 31;
    const int brow = (tid>>5)*4;
    float bi1v[3], bh1v[3];
    #pragma unroll
    for (int g=0; g<3; ++g){
      bi1v[g] = bi1[g*HDIM + u1+ua];
      bh1v[g] = bh [(3+g)*HDIM + u1+ua];
    }
    float h_own[4];
    #pragma unroll
    for (int j=0;j<4;++j) h_own[j]=0.f;

    unsigned tgt = 0;
    for (int s=0; s<=TLEN; ++s){
      if (s >= 1){
        const unsigned short* srcA = h0 + ((s-1)&1)*HSZ;   // h0(s-1)
        const unsigned short* srcB = h1 + (s&1)*HSZ;       // h1(s-2)
        unsigned short*       dstB = h1 + ((s-1)&1)*HSZ;   // h1(s-1)
        const unsigned short* mySrc = (w<2) ? srcA : srcB;
        unsigned short*       mySh  = (w<2) ? (unsigned short*)shA : (unsigned short*)shB;
        const unsigned short* shSrc = (w<2) ? (const unsigned short*)shA : (const unsigned short*)shB;
        const int rbase = 16*(w&1);
        uint4 st[8];
        #pragma unroll
        for (int i=0;i<8;++i){
          int r = rbase + 2*i + (lane>>5);
          st[i] = *(const uint4*)((const char*)mySrc + r*1024 + (lane&31)*16);
        }
        #pragma unroll
        for (int i=0;i<8;++i){
          int r = rbase + 2*i + (lane>>5);
          *(uint4*)((char*)mySh + r*528 + (lane&31)*16) = st[i];
        }
        __syncthreads();
        #pragma unroll
        for (int i=0;i<8;++i){
          int r = rbase + 2*i + (lane>>5);
          st[i] = *(const uint4*)((const char*)mySrc + r*1024 + 512 + (lane&31)*16);
        }
        f32x4 acc[2][3] = {};
        #pragma unroll
        for (int ks=0; ks<8; ++ks){
          int koff = (ks*32 + (lane>>4)*8)*2;
          bf16x8 a0 = *(const bf16x8*)((const char*)shSrc + (lane&15)*528 + koff);
          bf16x8 a1 = *(const bf16x8*)((const char*)shSrc + ((lane&15)+16)*528 + koff);
          #pragma unroll
          for (int nt=0; nt<3; ++nt){
            acc[0][nt] = __builtin_amdgcn_mfma_f32_16x16x32_bf16(a0, bfr[nt][ks], acc[0][nt],0,0,0);
            acc[1][nt] = __builtin_amdgcn_mfma_f32_16x16x32_bf16(a1, bfr[nt][ks], acc[1][nt],0,0,0);
          }
        }
        __syncthreads();
        #pragma unroll
        for (int i=0;i<8;++i){
          int r = rbase + 2*i + (lane>>5);
          *(uint4*)((char*)mySh + r*528 + (lane&31)*16) = st[i];
        }
        __syncthreads();
        #pragma unroll
        for (int ks=0; ks<8; ++ks){
          int koff = (ks*32 + (lane>>4)*8)*2;
          bf16x8 a0 = *(const bf16x8*)((const char*)shSrc + (lane&15)*528 + koff);
          bf16x8 a1 = *(const bf16x8*)((const char*)shSrc + ((lane&15)+16)*528 + koff);
          #pragma unroll
          for (int nt=0; nt<3; ++nt){
            acc[0][nt] = __builtin_amdgcn_mfma_f32_16x16x32_bf16(a0, bfr[nt][8+ks], acc[0][nt],0,0,0);
            acc[1][nt] = __builtin_amdgcn_mfma_f32_16x16x32_bf16(a1, bfr[nt][8+ks], acc[1][nt],0,0,0);
          }
        }
        #pragma unroll
        for (int mt=0; mt<2; ++mt)
          #pragma unroll
          for (int nt=0; nt<3; ++nt)
            #pragma unroll
            for (int j=0;j<4;++j){
              int b = mt*16 + (lane>>4)*4 + j;
              shG[b*192 + colb + nt*16 + (lane&15)] = acc[mt][nt][j];
            }
        __syncthreads();
        #pragma unroll
        for (int j=0;j<4;++j){
          int b = brow + j;
          float gi0 = shG[b*192 + ua]        + bi1v[0];
          float gi1 = shG[b*192 + 32 + ua]   + bi1v[1];
          float gi2 = shG[b*192 + 64 + ua]   + bi1v[2];
          float gh0 = shG[b*192 + 96 + ua]   + bh1v[0];
          float gh1 = shG[b*192 + 128 + ua]  + bh1v[1];
          float gh2 = shG[b*192 + 160 + ua]  + bh1v[2];
          float r_ = sigm(gi0+gh0);
          float z_ = sigm(gi1+gh1);
          float n_ = tanh_f(gi2 + r_*gh2);
          float hn = (1.f - z_)*n_ + z_*h_own[j];
          h_own[j] = hn;
          dstB[b*HDIM + u1 + ua] = f2bf(hn);
          if (s == TLEN) h1f[(size_t)(g32+b)*HDIM + u1 + ua] = hn;
        }
      }
      tgt += WPG;
      __threadfence();
      __syncthreads();
      if (tid==0){
        __hip_atomic_fetch_add(barp, 1u, __ATOMIC_RELEASE, __HIP_MEMORY_SCOPE_AGENT);
        while (__hip_atomic_load(barp, __ATOMIC_RELAXED, __HIP_MEMORY_SCOPE_AGENT) < tgt)
          __builtin_amdgcn_s_sleep(1);
      }
      __syncthreads();
      __threadfence();
    }
  }
}

extern "C" void kernel_launch(void* const* d_in, const int* in_sizes, int n_in,
                              void* d_out, int out_size, void* d_ws, size_t ws_size,
                              hipStream_t stream)
{
  const float* x   = (const float*)d_in[0];
  const float* Wi0 = (const float*)d_in[1];
  const float* bi0 = (const float*)d_in[2];
  const float* Wi1 = (const float*)d_in[3];
  const float* bi1 = (const float*)d_in[4];
  const float* Wh  = (const float*)d_in[5];
  const float* bh  = (const float*)d_in[6];
  const float* fcw = (const float*)d_in[7];
  const float* fcb = (const float*)d_in[8];
  float* out = (float*)d_out;

  // ws layout: [0,2048) barrier counters | h0 bufs | h1 bufs | fp32 h1_final
  unsigned*       bar = (unsigned*)d_ws;
  unsigned short* h0g = (unsigned short*)((char*)d_ws + 4096);
  unsigned short* h1g = (unsigned short*)((char*)d_ws + 4096 + 524288);
  float*          h1f = (float*)((char*)d_ws + 4096 + 2*524288);

  hipMemsetAsync(d_ws, 0, 4096 + 3*524288, stream);
  gru_persistent<<<GRID, 256, 0, stream>>>(x,Wi0,bi0,Wi1,bi1,Wh,bh,fcw,fcb,out,
                                           bar,h0g,h1g,h1f);
}

// Round 2
// 3511.942 us; speedup vs baseline: 4.8256x; 4.8256x over previous
//
#include <hip/hip_runtime.h>

#define TLEN 512
#define HDIM 512
#define NGRP 8
#define MROW 32
#define NL0  8
#define WPG  24
#define GRID (NGRP*WPG)
#define U0   64
#define U1   32
#define HSZ  (MROW*HDIM)   // elements per h buffer (one parity) per group
#define ROWB 1040          // LDS row stride bytes (1024B data + 16B pad; 260 dwords ≡ 4 mod 32 → 2-way max)

typedef __attribute__((ext_vector_type(8))) short bf16x8;
typedef __attribute__((ext_vector_type(4))) float f32x4;

#define AT_LD64(p)   __hip_atomic_load((const unsigned long long*)(p), __ATOMIC_RELAXED, __HIP_MEMORY_SCOPE_AGENT)
#define AT_ST16(p,v) __hip_atomic_store((unsigned short*)(p), (v), __ATOMIC_RELAXED, __HIP_MEMORY_SCOPE_AGENT)
#define AT_ST32F(p,v) __hip_atomic_store((float*)(p), (v), __ATOMIC_RELAXED, __HIP_MEMORY_SCOPE_AGENT)

__device__ __forceinline__ unsigned short f2bf(float f){
  unsigned u = __builtin_bit_cast(unsigned, f);
  u = (u + 0x7FFFu + ((u>>16)&1u)) >> 16;   // RNE
  return (unsigned short)u;
}
__device__ __forceinline__ float sigm(float v){ return 1.f/(1.f + __expf(-v)); }
__device__ __forceinline__ float tanh_f(float v){ return 1.f - 2.f/(__expf(2.f*v)+1.f); }

extern "C" __global__ void __launch_bounds__(256,1)
gru_persistent(const float* __restrict__ x,
               const float* __restrict__ Wi0,
               const float* __restrict__ bi0,
               const float* __restrict__ Wi1,
               const float* __restrict__ bi1,
               const float* __restrict__ Wh,
               const float* __restrict__ bh,
               const float* __restrict__ fcw,
               const float* __restrict__ fcb,
               float* __restrict__ out,
               unsigned* __restrict__ bar,
               unsigned short* __restrict__ h0g,
               unsigned short* __restrict__ h1g,
               float* __restrict__ h1f)
{
  __shared__ unsigned short shA[MROW*(ROWB/2)];
  __shared__ unsigned short shB[MROW*(ROWB/2)];
  __shared__ float shG[MROW*192];

  const int tid  = threadIdx.x;
  const int lane = tid & 63;
  const int w    = tid >> 6;
  const int grp  = blockIdx.x & 7;      // XCD-locality swizzle (perf heuristic only)
  const int wgid = blockIdx.x >> 3;     // 0..23
  const bool isL0 = (wgid < NL0);
  const int g32 = grp*32;

  unsigned* barp = bar + grp*64;                 // 256B-separated counters
  unsigned short* h0 = h0g + grp*2*HSZ;
  unsigned short* h1 = h1g + grp*2*HSZ;

  if (isL0){
    // ---------------- layer-0 workgroup: units [u0, u0+64) ----------------
    const int u0   = wgid*U0;
    const int colb = w*48;               // this wave's 48 cols of 192 (col = g*64+u)

    bf16x8 bfr[3][16];                   // pinned weight fragments (whole kernel)
    #pragma unroll
    for (int nt=0; nt<3; ++nt){
      int col = colb + nt*16 + (lane&15);
      int g = col>>6, uu = col&63;
      const float* wrow = Wh + (size_t)(g*HDIM + u0 + uu)*HDIM;   // Wh[0][g][u][:]
      #pragma unroll
      for (int ks=0; ks<16; ++ks){
        int k = ks*32 + (lane>>4)*8;
        const float4 f0 = *(const float4*)(wrow + k);
        const float4 f1 = *(const float4*)(wrow + k + 4);
        bf16x8 v;
        v[0]=(short)f2bf(f0.x); v[1]=(short)f2bf(f0.y); v[2]=(short)f2bf(f0.z); v[3]=(short)f2bf(f0.w);
        v[4]=(short)f2bf(f1.x); v[5]=(short)f2bf(f1.y); v[6]=(short)f2bf(f1.z); v[7]=(short)f2bf(f1.w);
        bfr[nt][ks]=v;
      }
    }
    const int ua   = tid & 63;
    const int brow = (tid>>6)*8;
    float wi0v[3], bi0v[3], bh0v[3];
    #pragma unroll
    for (int g=0; g<3; ++g){
      wi0v[g] = Wi0[g*HDIM + u0+ua];
      bi0v[g] = bi0[g*HDIM + u0+ua];
      bh0v[g] = bh [g*HDIM + u0+ua];
    }
    float h_own[8];
    #pragma unroll
    for (int j=0;j<8;++j) h_own[j]=0.f;

    unsigned tgt = 0;
    for (int s=0; s<=TLEN; ++s){
      if (s < TLEN){
        const unsigned short* srcA = h0 + ((s-1)&1)*HSZ;   // h0(s-1)
        unsigned short*       dstA = h0 + (s&1)*HSZ;       // h0(s)
        // ---- stage full-K h0(s-1) via coherent (sc1) loads ----
        unsigned long long hb[16];
        #pragma unroll
        for (int i=0;i<16;++i)
          hb[i] = AT_LD64((const char*)srcA + tid*8 + i*2048);
        #pragma unroll
        for (int i=0;i<16;++i){
          int flat = tid*8 + i*2048;
          *(unsigned long long*)((char*)shA + (flat>>10)*ROWB + (flat&1023)) = hb[i];
        }
        __syncthreads();
        f32x4 acc[2][3] = {};
        #pragma unroll
        for (int ks=0; ks<16; ++ks){
          int koff = ks*64 + (lane>>4)*16;
          bf16x8 a0 = *(const bf16x8*)((const char*)shA + (lane&15)*ROWB + koff);
          bf16x8 a1 = *(const bf16x8*)((const char*)shA + ((lane&15)+16)*ROWB + koff);
          #pragma unroll
          for (int nt=0; nt<3; ++nt){
            acc[0][nt] = __builtin_amdgcn_mfma_f32_16x16x32_bf16(a0, bfr[nt][ks], acc[0][nt],0,0,0);
            acc[1][nt] = __builtin_amdgcn_mfma_f32_16x16x32_bf16(a1, bfr[nt][ks], acc[1][nt],0,0,0);
          }
        }
        // gate sums → LDS. C layout: row(b)=4*quad+reg, col=lane&15
        #pragma unroll
        for (int mt=0; mt<2; ++mt)
          #pragma unroll
          for (int nt=0; nt<3; ++nt)
            #pragma unroll
            for (int j=0;j<4;++j){
              int b = mt*16 + (lane>>4)*4 + j;
              shG[b*192 + colb + nt*16 + (lane&15)] = acc[mt][nt][j];
            }
        __syncthreads();
        // activation (fp32 own-state path), publish via coherent stores
        #pragma unroll
        for (int j=0;j<8;++j){
          int b = brow + j;
          float xv = x[(g32+b)*TLEN + s];
          float G0 = shG[b*192 + ua]       + bh0v[0];
          float G1 = shG[b*192 + 64 + ua]  + bh0v[1];
          float G2 = shG[b*192 + 128 + ua] + bh0v[2];
          float r_ = sigm(fmaf(xv, wi0v[0], bi0v[0]) + G0);
          float z_ = sigm(fmaf(xv, wi0v[1], bi0v[1]) + G1);
          float n_ = tanh_f(fmaf(xv, wi0v[2], bi0v[2]) + r_*G2);
          float hn = (1.f - z_)*n_ + z_*h_own[j];
          h_own[j] = hn;
          AT_ST16(&dstA[b*HDIM + u0 + ua], f2bf(hn));
        }
      }
      // ---- group barrier: drain coherent stores, no L2 flush ----
      tgt += WPG;
      asm volatile("s_waitcnt vmcnt(0)" ::: "memory");
      __syncthreads();
      if (tid==0){
        __hip_atomic_fetch_add(barp, 1u, __ATOMIC_RELAXED, __HIP_MEMORY_SCOPE_AGENT);
        while (__hip_atomic_load(barp, __ATOMIC_RELAXED, __HIP_MEMORY_SCOPE_AGENT) < tgt)
          __builtin_amdgcn_s_sleep(1);
      }
      __syncthreads();
    }
    // final FC: 32 rows x 2 outputs, done by WG0 of the group
    if (wgid==0){
      int p = tid>>2, kl = tid&3;
      int b = p>>1, o = p&1;
      const char* h8 = (const char*)(h1f + (size_t)(g32+b)*HDIM + kl*128);
      const float2* w2 = (const float2*)(fcw + o*HDIM + kl*128);
      float a2 = 0.f;
      #pragma unroll
      for (int k=0;k<64;++k){
        unsigned long long v = AT_LD64(h8 + k*8);
        float2 hv = __builtin_bit_cast(float2, v);
        float2 wv = w2[k];
        a2 = fmaf(hv.x, wv.x, fmaf(hv.y, wv.y, a2));
      }
      a2 += __shfl_xor(a2, 1);
      a2 += __shfl_xor(a2, 2);
      if (kl==0) out[(g32+b)*2 + o] = a2 + fcb[o];
    }
  } else {
    // ---------------- layer-1 workgroup: units [u1, u1+32) ----------------
    const int u1   = (wgid-NL0)*U1;
    const int colb = (w<2) ? w*48 : 96 + (w-2)*48;  // cols 0..95 gi, 96..191 gh

    bf16x8 bfr[3][16];
    #pragma unroll
    for (int nt=0; nt<3; ++nt){
      int col = colb + nt*16 + (lane&15);
      const float* wrow;
      if (w < 2){ int g = col>>5, uu = col&31;
        wrow = Wi1 + (size_t)(g*HDIM + u1 + uu)*HDIM;             // Wi_rest[0][g][u][:]
      } else {    int c2 = col-96; int g = c2>>5, uu = c2&31;
        wrow = Wh + (size_t)((3+g)*HDIM + u1 + uu)*HDIM;          // Wh[1][g][u][:]
      }
      #pragma unroll
      for (int ks=0; ks<16; ++ks){
        int k = ks*32 + (lane>>4)*8;
        const float4 f0 = *(const float4*)(wrow + k);
        const float4 f1 = *(const float4*)(wrow + k + 4);
        bf16x8 v;
        v[0]=(short)f2bf(f0.x); v[1]=(short)f2bf(f0.y); v[2]=(short)f2bf(f0.z); v[3]=(short)f2bf(f0.w);
        v[4]=(short)f2bf(f1.x); v[5]=(short)f2bf(f1.y); v[6]=(short)f2bf(f1.z); v[7]=(short)f2bf(f1.w);
        bfr[nt][ks]=v;
      }
    }
    const int ua   = tid & 31;
    const int brow = (tid>>5)*4;
    float bi1v[3], bh1v[3];
    #pragma unroll
    for (int g=0; g<3; ++g){
      bi1v[g] = bi1[g*HDIM + u1+ua];
      bh1v[g] = bh [(3+g)*HDIM + u1+ua];
    }
    float h_own[4];
    #pragma unroll
    for (int j=0;j<4;++j) h_own[j]=0.f;

    unsigned tgt = 0;
    for (int s=0; s<=TLEN; ++s){
      if (s >= 1){
        const unsigned short* srcA = h0 + ((s-1)&1)*HSZ;   // h0(s-1)
        const unsigned short* srcB = h1 + (s&1)*HSZ;       // h1(s-2)
        unsigned short*       dstB = h1 + ((s-1)&1)*HSZ;   // h1(s-1)
        unsigned long long hb[16];
        #pragma unroll
        for (int i=0;i<16;++i)
          hb[i] = AT_LD64((const char*)srcA + tid*8 + i*2048);
        #pragma unroll
        for (int i=0;i<16;++i){
          int flat = tid*8 + i*2048;
          *(unsigned long long*)((char*)shA + (flat>>10)*ROWB + (flat&1023)) = hb[i];
        }
        #pragma unroll
        for (int i=0;i<16;++i)
          hb[i] = AT_LD64((const char*)srcB + tid*8 + i*2048);
        #pragma unroll
        for (int i=0;i<16;++i){
          int flat = tid*8 + i*2048;
          *(unsigned long long*)((char*)shB + (flat>>10)*ROWB + (flat&1023)) = hb[i];
        }
        __syncthreads();
        const char* shSrc = (w<2) ? (const char*)shA : (const char*)shB;
        f32x4 acc[2][3] = {};
        #pragma unroll
        for (int ks=0; ks<16; ++ks){
          int koff = ks*64 + (lane>>4)*16;
          bf16x8 a0 = *(const bf16x8*)(shSrc + (lane&15)*ROWB + koff);
          bf16x8 a1 = *(const bf16x8*)(shSrc + ((lane&15)+16)*ROWB + koff);
          #pragma unroll
          for (int nt=0; nt<3; ++nt){
            acc[0][nt] = __builtin_amdgcn_mfma_f32_16x16x32_bf16(a0, bfr[nt][ks], acc[0][nt],0,0,0);
            acc[1][nt] = __builtin_amdgcn_mfma_f32_16x16x32_bf16(a1, bfr[nt][ks], acc[1][nt],0,0,0);
          }
        }
        #pragma unroll
        for (int mt=0; mt<2; ++mt)
          #pragma unroll
          for (int nt=0; nt<3; ++nt)
            #pragma unroll
            for (int j=0;j<4;++j){
              int b = mt*16 + (lane>>4)*4 + j;
              shG[b*192 + colb + nt*16 + (lane&15)] = acc[mt][nt][j];
            }
        __syncthreads();
        #pragma unroll
        for (int j=0;j<4;++j){
          int b = brow + j;
          float gi0 = shG[b*192 + ua]        + bi1v[0];
          float gi1 = shG[b*192 + 32 + ua]   + bi1v[1];
          float gi2 = shG[b*192 + 64 + ua]   + bi1v[2];
          float gh0 = shG[b*192 + 96 + ua]   + bh1v[0];
          float gh1 = shG[b*192 + 128 + ua]  + bh1v[1];
          float gh2 = shG[b*192 + 160 + ua]  + bh1v[2];
          float r_ = sigm(gi0+gh0);
          float z_ = sigm(gi1+gh1);
          float n_ = tanh_f(gi2 + r_*gh2);
          float hn = (1.f - z_)*n_ + z_*h_own[j];
          h_own[j] = hn;
          AT_ST16(&dstB[b*HDIM + u1 + ua], f2bf(hn));
          if (s == TLEN) AT_ST32F(&h1f[(size_t)(g32+b)*HDIM + u1 + ua], hn);
        }
      }
      tgt += WPG;
      asm volatile("s_waitcnt vmcnt(0)" ::: "memory");
      __syncthreads();
      if (tid==0){
        __hip_atomic_fetch_add(barp, 1u, __ATOMIC_RELAXED, __HIP_MEMORY_SCOPE_AGENT);
        while (__hip_atomic_load(barp, __ATOMIC_RELAXED, __HIP_MEMORY_SCOPE_AGENT) < tgt)
          __builtin_amdgcn_s_sleep(1);
      }
      __syncthreads();
    }
  }
}

extern "C" void kernel_launch(void* const* d_in, const int* in_sizes, int n_in,
                              void* d_out, int out_size, void* d_ws, size_t ws_size,
                              hipStream_t stream)
{
  const float* x   = (const float*)d_in[0];
  const float* Wi0 = (const float*)d_in[1];
  const float* bi0 = (const float*)d_in[2];
  const float* Wi1 = (const float*)d_in[3];
  const float* bi1 = (const float*)d_in[4];
  const float* Wh  = (const float*)d_in[5];
  const float* bh  = (const float*)d_in[6];
  const float* fcw = (const float*)d_in[7];
  const float* fcb = (const float*)d_in[8];
  float* out = (float*)d_out;

  // ws layout: [0,4096) barrier counters | h0 bufs | h1 bufs | fp32 h1_final
  unsigned*       bar = (unsigned*)d_ws;
  unsigned short* h0g = (unsigned short*)((char*)d_ws + 4096);
  unsigned short* h1g = (unsigned short*)((char*)d_ws + 4096 + 524288);
  float*          h1f = (float*)((char*)d_ws + 4096 + 2*524288);

  hipMemsetAsync(d_ws, 0, 4096 + 3*524288, stream);
  gru_persistent<<<GRID, 256, 0, stream>>>(x,Wi0,bi0,Wi1,bi1,Wh,bh,fcw,fcb,out,
                                           bar,h0g,h1g,h1f);
}